// Round 4
// baseline (1932.194 us; speedup 1.0000x reference)
//
#include <hip/hip_runtime.h>

#define N_NODES 100000
#define N_EDGES 3200000
#define F_IN    128
#define HC      32      // H*C
#define CH      16      // C per head
#define NGRAPH  64
#define NEG     0.2f

#define BSH   7                                   // 128 nodes per bucket
#define BNODE (1 << BSH)
#define NB2   ((N_NODES + BNODE - 1) >> BSH)      // 782 buckets
#define EPB2  8192                                // edges per k_bucket block

__device__ __forceinline__ float lrelu(float x) { return x > 0.f ? x : NEG * x; }

// ---------- reductions / small precompute ----------

__global__ void k_ea_sum(const float* __restrict__ ea, float* __restrict__ params) {
    float acc = 0.f;
    for (int i = blockIdx.x * blockDim.x + threadIdx.x; i < N_EDGES;
         i += gridDim.x * blockDim.x)
        acc += ea[i];
    for (int m = 32; m >= 1; m >>= 1) acc += __shfl_xor(acc, m, 64);
    __shared__ float sh[4];
    int lane = threadIdx.x & 63, wid = threadIdx.x >> 6;
    if (lane == 0) sh[wid] = acc;
    __syncthreads();
    if (threadIdx.x == 0) {
        float t = 0.f;
        for (int i = 0; i < 4; ++i) t += sh[i];
        unsafeAtomicAdd(params, t);
    }
}

// params: [0]=ea_sum, [1]=ea_mean, [2..3]=ce layer1, [4..5]=ce layer2
__global__ void k_prep(const float* __restrict__ We1, const float* __restrict__ ae1,
                       const float* __restrict__ We2, const float* __restrict__ ae2,
                       float* __restrict__ params) {
    int t = threadIdx.x;
    if (t < 2) {
        float c1 = 0.f, c2 = 0.f;
        for (int c = 0; c < CH; ++c) {
            c1 += We1[t * CH + c] * ae1[t * CH + c];
            c2 += We2[t * CH + c] * ae2[t * CH + c];
        }
        params[2 + t] = c1;
        params[4 + t] = c2;
        if (t == 0) params[1] = params[0] / (float)N_EDGES;
    }
}

// ---------- bucket histogram (782 bins) + scan ----------

__global__ void k_bhist(const int* __restrict__ dst, int* __restrict__ cnt) {
    __shared__ int l[NB2];
    for (int i = threadIdx.x; i < NB2; i += 256) l[i] = 0;
    __syncthreads();
    for (int e = blockIdx.x * blockDim.x + threadIdx.x; e < N_EDGES;
         e += gridDim.x * blockDim.x)
        atomicAdd(&l[dst[e] >> BSH], 1);
    __syncthreads();
    for (int i = threadIdx.x; i < NB2; i += 256)
        if (l[i]) atomicAdd(&cnt[i], l[i]);
}

__global__ void k_bscan(const int* __restrict__ cnt, int* __restrict__ gstart,
                        int* __restrict__ gcur) {
    __shared__ int sh[256];
    int t = threadIdx.x;
    int v[4];
    int s = 0;
    for (int j = 0; j < 4; ++j) {
        int i = t * 4 + j;
        v[j] = (i < NB2) ? cnt[i] : 0;
        s += v[j];
    }
    sh[t] = s;
    __syncthreads();
    for (int off = 1; off < 256; off <<= 1) {
        int u = (t >= off) ? sh[t - off] : 0;
        __syncthreads();
        sh[t] += u;
        __syncthreads();
    }
    int ex = sh[t] - s;   // exclusive prefix
    for (int j = 0; j < 4; ++j) {
        int i = t * 4 + j;
        if (i < NB2) { gstart[i] = ex; gcur[i] = ex; ex += v[j]; }
    }
    if (t == 255) gstart[NB2] = N_EDGES;
}

// ---------- single-pass bucket scatter (packed 8B records) ----------

__global__ void k_bucket(const int* __restrict__ src, const int* __restrict__ dst,
                         const float* __restrict__ ea, int* __restrict__ gcur,
                         int2* __restrict__ staged) {
    __shared__ int lcur[NB2];
    __shared__ int gbase[NB2];
    int t = threadIdx.x;
    for (int i = t; i < NB2; i += 256) lcur[i] = 0;
    __syncthreads();
    int base = blockIdx.x * EPB2;
    int rank[EPB2 / 256];
#pragma unroll
    for (int i = 0; i < EPB2 / 256; ++i) {
        int e = base + i * 256 + t;
        if (e < N_EDGES) rank[i] = atomicAdd(&lcur[dst[e] >> BSH], 1);
    }
    __syncthreads();
    for (int i = t; i < NB2; i += 256)
        if (lcur[i] > 0) gbase[i] = atomicAdd(&gcur[i], lcur[i]);
    __syncthreads();
#pragma unroll
    for (int i = 0; i < EPB2 / 256; ++i) {
        int e = base + i * 256 + t;
        if (e < N_EDGES) {
            int dv = dst[e];
            staged[gbase[dv >> BSH] + rank[i]] =
                make_int2((src[e] << BSH) | (dv & (BNODE - 1)), __float_as_int(ea[e]));
        }
    }
}

// ---------- dense: h = x @ W, plus fused asrc/adst ----------

template <int FIN>
__global__ void k_linear(const float* __restrict__ x, const float* __restrict__ W,
                         const float* __restrict__ a_src, const float* __restrict__ a_dst,
                         float* __restrict__ h, float* __restrict__ asrc,
                         float* __restrict__ adst) {
    int tid = blockIdx.x * blockDim.x + threadIdx.x;
    int n = tid >> 5;
    if (n >= N_NODES) return;
    int c = tid & 31;
    const float* xr = x + (size_t)n * FIN;
    float acc = 0.f;
#pragma unroll 8
    for (int k = 0; k < FIN; ++k) acc = fmaf(xr[k], W[k * HC + c], acc);
    h[(size_t)n * HC + c] = acc;
    int hh = c >> 4, cc = c & 15;
    float vs = acc * a_src[hh * CH + cc];
    float vd = acc * a_dst[hh * CH + cc];
    for (int m = 8; m >= 1; m >>= 1) {
        vs += __shfl_xor(vs, m, 16);
        vd += __shfl_xor(vd, m, 16);
    }
    if (cc == 0) {
        asrc[n * 2 + hh] = vs;
        adst[n * 2 + hh] = vd;
    }
}

// ---------- fused GAT layer: one block per 128-node bucket, LDS accumulate ----------

__global__ __launch_bounds__(256, 8)
void k_gat(const int* __restrict__ gstart, const int2* __restrict__ staged,
           const float* __restrict__ h,
           const float* __restrict__ asrc, const float* __restrict__ adst,
           const float* __restrict__ params, int ceoff,
           const float* __restrict__ bias, int do_relu,
           float* __restrict__ out) {
    __shared__ float acc[BNODE * HC];     // 16 KB
    __shared__ float ssum[BNODE * 2];     // 1 KB
    __shared__ float sh_adst[BNODE * 2];  // 1 KB
    int b = blockIdx.x, t = threadIdx.x;
    int nbase = b << BSH;
    int bcount = N_NODES - nbase;
    if (bcount > BNODE) bcount = BNODE;

    for (int i = t; i < BNODE * HC; i += 256) acc[i] = 0.f;
    for (int i = t; i < BNODE * 2; i += 256) {
        ssum[i] = 0.f;
        int n = nbase + (i >> 1);
        sh_adst[i] = (n < N_NODES) ? adst[n * 2 + (i & 1)] : 0.f;
    }
    __syncthreads();

    int est = gstart[b], een = gstart[b + 1];
    int c = t & 31, sub = t >> 5, hh = c >> 4;
    float ce = params[ceoff + hh];
    for (int e = est + sub; e < een; e += 8) {
        int2 r = staged[e];
        int sv = r.x >> BSH;
        int dloc = r.x & (BNODE - 1);
        float eav = __int_as_float(r.y);
        float asv = asrc[sv * 2 + hh];
        float hv = h[(size_t)sv * HC + c];
        float wv = __expf(lrelu(asv + sh_adst[dloc * 2 + hh] + ce * eav));
        atomicAdd(&acc[dloc * HC + c], wv * hv);
        if ((c & 15) == 0) atomicAdd(&ssum[dloc * 2 + hh], wv);
    }
    __syncthreads();

    float eam = params[1];
    for (int i = t; i < bcount * HC; i += 256) {
        int dloc = i >> 5, cc = i & 31, h2 = (i >> 4) & 1;
        int n = nbase + dloc;
        float wself = __expf(lrelu(asrc[n * 2 + h2] + sh_adst[dloc * 2 + h2] +
                                   params[ceoff + h2] * eam));
        float v = (acc[i] + wself * h[(size_t)n * HC + cc]) /
                  (ssum[dloc * 2 + h2] + wself + 1e-16f) + bias[cc];
        if (do_relu) v = fmaxf(v, 0.f);
        out[(size_t)n * HC + cc] = v;
    }
}

// ---------- batch pooling (batch is sorted) ----------

__global__ void k_bounds(const int* __restrict__ batch, int* __restrict__ se) {
    int i = blockIdx.x * blockDim.x + threadIdx.x;
    if (i >= N_NODES) return;
    int b = batch[i];
    if (i == 0 || batch[i - 1] != b) se[b] = i;
    if (i == N_NODES - 1 || batch[i + 1] != b) se[NGRAPH + b] = i + 1;
}

__global__ void k_pool(const float* __restrict__ feat, const int* __restrict__ se,
                       float* __restrict__ emb) {
    int g = blockIdx.x;
    int st = se[g], en = se[NGRAPH + g];
    int c = threadIdx.x & 31, r = threadIdx.x >> 5;  // r in 0..7
    float acc = 0.f;
    for (int n = st + r; n < en; n += 8) acc += feat[(size_t)n * HC + c];
    __shared__ float sh[8][32];
    sh[r][c] = acc;
    __syncthreads();
    if (threadIdx.x < 32) {
        float t = 0.f;
        for (int r2 = 0; r2 < 8; ++r2) t += sh[r2][c];
        int cnt = en - st;
        emb[g * HC + c] = t / (float)(cnt > 0 ? cnt : 1);
    }
}

// ---------- tiny MLP head ----------

__global__ void k_mlp(const float* __restrict__ emb, const float* __restrict__ Wf1,
                      const float* __restrict__ bf1, const float* __restrict__ Wf2,
                      const float* __restrict__ bf2, float* __restrict__ out) {
    int g = blockIdx.x, j = threadIdx.x;  // 32 threads
    __shared__ float hid[32];
    float a = bf1[j];
    for (int k = 0; k < 32; ++k) a = fmaf(emb[g * 32 + k], Wf1[k * 32 + j], a);
    hid[j] = fmaxf(a, 0.f);
    __syncthreads();
    if (j < 2) {
        float o = bf2[j];
        for (int k = 0; k < 32; ++k) o = fmaf(hid[k], Wf2[k * 2 + j], o);
        out[g * 2 + j] = o;
    }
}

extern "C" void kernel_launch(void* const* d_in, const int* in_sizes, int n_in,
                              void* d_out, int out_size, void* d_ws, size_t ws_size,
                              hipStream_t stream) {
    const float* x   = (const float*)d_in[0];
    const int*   ei  = (const int*)d_in[1];
    const float* ea  = (const float*)d_in[2];
    const int* batch = (const int*)d_in[3];
    const float* W1  = (const float*)d_in[4];
    const float* as1 = (const float*)d_in[5];
    const float* ad1 = (const float*)d_in[6];
    const float* We1 = (const float*)d_in[7];
    const float* ae1 = (const float*)d_in[8];
    const float* b1  = (const float*)d_in[9];
    const float* W2  = (const float*)d_in[10];
    const float* as2 = (const float*)d_in[11];
    const float* ad2 = (const float*)d_in[12];
    const float* We2 = (const float*)d_in[13];
    const float* ae2 = (const float*)d_in[14];
    const float* b2  = (const float*)d_in[15];
    const float* Wf1 = (const float*)d_in[16];
    const float* bf1 = (const float*)d_in[17];
    const float* Wf2 = (const float*)d_in[18];
    const float* bf2 = (const float*)d_in[19];
    float* out = (float*)d_out;
    (void)in_sizes; (void)n_in; (void)out_size; (void)ws_size;

    const int* srcp = ei;
    const int* dstp = ei + N_EDGES;

    char* wsb = (char*)d_ws;
    size_t off = 0;
    auto alloc = [&](size_t bytes) -> char* {
        char* p = wsb + off;
        off = (off + bytes + 255) & ~(size_t)255;
        return p;
    };
    float* params = (float*)alloc(64);
    int2*  staged = (int2*)alloc((size_t)N_EDGES * 8);          // persists both layers
    float* hbuf   = (float*)alloc((size_t)N_NODES * HC * 4);
    float* obuf   = (float*)alloc((size_t)N_NODES * HC * 4);
    float* asrc   = (float*)alloc((size_t)N_NODES * 2 * 4);
    float* adst   = (float*)alloc((size_t)N_NODES * 2 * 4);
    int*   cnt    = (int*)alloc((size_t)NB2 * 4);
    int*   gstart = (int*)alloc((size_t)(NB2 + 1) * 4);
    int*   gcur   = (int*)alloc((size_t)NB2 * 4);
    float* emb    = (float*)alloc(NGRAPH * HC * 4);
    int*   se     = (int*)alloc(2 * NGRAPH * 4);

    hipMemsetAsync(params, 0, 64, stream);
    hipMemsetAsync(cnt, 0, (size_t)NB2 * 4, stream);
    hipMemsetAsync(se, 0, 2 * NGRAPH * 4, stream);

    const int nThr = N_NODES * HC;  // 3.2M
    const int nBlk = (nThr + 255) / 256;
    const int nBlkN = (N_NODES + 255) / 256;
    const int nBlkB = (N_EDGES + EPB2 - 1) / EPB2;

    // precompute + bucket build
    k_ea_sum<<<1024, 256, 0, stream>>>(ea, params);
    k_prep<<<1, 64, 0, stream>>>(We1, ae1, We2, ae2, params);
    k_bhist<<<1024, 256, 0, stream>>>(dstp, cnt);
    k_bscan<<<1, 256, 0, stream>>>(cnt, gstart, gcur);
    k_bucket<<<nBlkB, 256, 0, stream>>>(srcp, dstp, ea, gcur, staged);

    // ----- layer 1 -----
    k_linear<F_IN><<<nBlk, 256, 0, stream>>>(x, W1, as1, ad1, hbuf, asrc, adst);
    k_gat<<<NB2, 256, 0, stream>>>(gstart, staged, hbuf, asrc, adst, params, 2, b1, 1, obuf);

    // ----- layer 2 -----
    k_linear<HC><<<nBlk, 256, 0, stream>>>(obuf, W2, as2, ad2, hbuf, asrc, adst);
    k_gat<<<NB2, 256, 0, stream>>>(gstart, staged, hbuf, asrc, adst, params, 4, b2, 0, obuf);

    // ----- pool + MLP -----
    k_bounds<<<nBlkN, 256, 0, stream>>>(batch, se);
    k_pool<<<NGRAPH, 256, 0, stream>>>(obuf, se, emb);
    k_mlp<<<NGRAPH, 32, 0, stream>>>(emb, Wf1, bf1, Wf2, bf2, out);
}

// Round 5
// 630.109 us; speedup vs baseline: 3.0664x; 3.0664x over previous
//
#include <hip/hip_runtime.h>

#define N_NODES 100000
#define N_EDGES 3200000
#define F_IN    128
#define HC      32      // H*C
#define CH      16      // C per head
#define NGRAPH  64
#define NEG     0.2f

#define BSH   7                                   // 128 nodes per bucket
#define BNODE (1 << BSH)
#define NB2   ((N_NODES + BNODE - 1) >> BSH)      // 782 buckets
#define EPB2  8192                                // edges per k_bucket block

__device__ __forceinline__ float lrelu(float x) { return x > 0.f ? x : NEG * x; }

// ---------- reductions / small precompute ----------

__global__ void k_ea_sum(const float* __restrict__ ea, float* __restrict__ params) {
    float acc = 0.f;
    for (int i = blockIdx.x * blockDim.x + threadIdx.x; i < N_EDGES;
         i += gridDim.x * blockDim.x)
        acc += ea[i];
    for (int m = 32; m >= 1; m >>= 1) acc += __shfl_xor(acc, m, 64);
    __shared__ float sh[4];
    int lane = threadIdx.x & 63, wid = threadIdx.x >> 6;
    if (lane == 0) sh[wid] = acc;
    __syncthreads();
    if (threadIdx.x == 0) {
        float t = 0.f;
        for (int i = 0; i < 4; ++i) t += sh[i];
        unsafeAtomicAdd(params, t);
    }
}

// params: [0]=ea_sum, [1]=ea_mean, [2..3]=ce layer1, [4..5]=ce layer2
__global__ void k_prep(const float* __restrict__ We1, const float* __restrict__ ae1,
                       const float* __restrict__ We2, const float* __restrict__ ae2,
                       float* __restrict__ params) {
    int t = threadIdx.x;
    if (t < 2) {
        float c1 = 0.f, c2 = 0.f;
        for (int c = 0; c < CH; ++c) {
            c1 += We1[t * CH + c] * ae1[t * CH + c];
            c2 += We2[t * CH + c] * ae2[t * CH + c];
        }
        params[2 + t] = c1;
        params[4 + t] = c2;
        if (t == 0) params[1] = params[0] / (float)N_EDGES;
    }
}

// ---------- bucket histogram (782 bins) + scan ----------

__global__ void k_bhist(const int* __restrict__ dst, int* __restrict__ cnt) {
    __shared__ int l[NB2];
    for (int i = threadIdx.x; i < NB2; i += 256) l[i] = 0;
    __syncthreads();
    for (int e = blockIdx.x * blockDim.x + threadIdx.x; e < N_EDGES;
         e += gridDim.x * blockDim.x)
        atomicAdd(&l[dst[e] >> BSH], 1);
    __syncthreads();
    for (int i = threadIdx.x; i < NB2; i += 256)
        if (l[i]) atomicAdd(&cnt[i], l[i]);
}

__global__ void k_bscan(const int* __restrict__ cnt, int* __restrict__ gstart,
                        int* __restrict__ gcur, int* __restrict__ rowptr) {
    __shared__ int sh[256];
    int t = threadIdx.x;
    int v[4];
    int s = 0;
    for (int j = 0; j < 4; ++j) {
        int i = t * 4 + j;
        v[j] = (i < NB2) ? cnt[i] : 0;
        s += v[j];
    }
    sh[t] = s;
    __syncthreads();
    for (int off = 1; off < 256; off <<= 1) {
        int u = (t >= off) ? sh[t - off] : 0;
        __syncthreads();
        sh[t] += u;
        __syncthreads();
    }
    int ex = sh[t] - s;   // exclusive prefix
    for (int j = 0; j < 4; ++j) {
        int i = t * 4 + j;
        if (i < NB2) { gstart[i] = ex; gcur[i] = ex; ex += v[j]; }
    }
    if (t == 255) {
        gstart[NB2] = N_EDGES;
        rowptr[N_NODES] = N_EDGES;
    }
}

// ---------- pass A: bucket scatter (packed 8B records) ----------

__global__ void k_bucket(const int* __restrict__ src, const int* __restrict__ dst,
                         const float* __restrict__ ea, int* __restrict__ gcur,
                         int2* __restrict__ staged) {
    __shared__ int lcur[NB2];
    __shared__ int gbase[NB2];
    int t = threadIdx.x;
    for (int i = t; i < NB2; i += 256) lcur[i] = 0;
    __syncthreads();
    int base = blockIdx.x * EPB2;
    int rank[EPB2 / 256];
#pragma unroll
    for (int i = 0; i < EPB2 / 256; ++i) {
        int e = base + i * 256 + t;
        if (e < N_EDGES) rank[i] = atomicAdd(&lcur[dst[e] >> BSH], 1);
    }
    __syncthreads();
    for (int i = t; i < NB2; i += 256)
        if (lcur[i] > 0) gbase[i] = atomicAdd(&gcur[i], lcur[i]);
    __syncthreads();
#pragma unroll
    for (int i = 0; i < EPB2 / 256; ++i) {
        int e = base + i * 256 + t;
        if (e < N_EDGES) {
            int dv = dst[e];
            staged[gbase[dv >> BSH] + rank[i]] =
                make_int2((src[e] << BSH) | (dv & (BNODE - 1)), __float_as_int(ea[e]));
        }
    }
}

// ---------- pass B: per-bucket local hist+scan, write rowptr + per-node-sorted epack ----------

__global__ void k_scatter(const int2* __restrict__ staged, const int* __restrict__ gstart,
                          int* __restrict__ rowptr, int2* __restrict__ epack) {
    __shared__ int cntl[BNODE];
    __shared__ int scanb[BNODE];
    __shared__ int cur[BNODE];
    int b = blockIdx.x, t = threadIdx.x;
    int nbase = b << BSH;
    int bcount = N_NODES - nbase;
    if (bcount > BNODE) bcount = BNODE;
    if (t < BNODE) cntl[t] = 0;
    __syncthreads();
    int st = gstart[b], en = gstart[b + 1];
    for (int e = st + t; e < en; e += 256)
        atomicAdd(&cntl[staged[e].x & (BNODE - 1)], 1);
    __syncthreads();
    if (t < BNODE) scanb[t] = cntl[t];
    __syncthreads();
    for (int off = 1; off < BNODE; off <<= 1) {
        int u = (t < BNODE && t >= off) ? scanb[t - off] : 0;
        __syncthreads();
        if (t < BNODE) scanb[t] += u;
        __syncthreads();
    }
    if (t < BNODE) {
        int ex = st + scanb[t] - cntl[t];   // exclusive, global
        cur[t] = ex;
        if (t < bcount) rowptr[nbase + t] = ex;
    }
    __syncthreads();
    for (int e = st + t; e < en; e += 256) {
        int2 r = staged[e];
        int pos = atomicAdd(&cur[r.x & (BNODE - 1)], 1);
        epack[pos] = r;
    }
}

// ---------- dense: h = x @ W, plus fused asrc/adst ----------

template <int FIN>
__global__ void k_linear(const float* __restrict__ x, const float* __restrict__ W,
                         const float* __restrict__ a_src, const float* __restrict__ a_dst,
                         float* __restrict__ h, float* __restrict__ asrc,
                         float* __restrict__ adst) {
    int tid = blockIdx.x * blockDim.x + threadIdx.x;
    int n = tid >> 5;
    if (n >= N_NODES) return;
    int c = tid & 31;
    const float* xr = x + (size_t)n * FIN;
    float acc = 0.f;
#pragma unroll 8
    for (int k = 0; k < FIN; ++k) acc = fmaf(xr[k], W[k * HC + c], acc);
    h[(size_t)n * HC + c] = acc;
    int hh = c >> 4, cc = c & 15;
    float vs = acc * a_src[hh * CH + cc];
    float vd = acc * a_dst[hh * CH + cc];
    for (int m = 8; m >= 1; m >>= 1) {
        vs += __shfl_xor(vs, m, 16);
        vd += __shfl_xor(vd, m, 16);
    }
    if (cc == 0) {
        asrc[n * 2 + hh] = vs;
        adst[n * 2 + hh] = vd;
    }
}

// ---------- fused GAT layer: gather form, register accumulate, 4x unrolled ----------

__global__ void k_gat(const int* __restrict__ rowptr, const int2* __restrict__ epack,
                      const float* __restrict__ h,
                      const float* __restrict__ asrc, const float* __restrict__ adst,
                      const float* __restrict__ params, int ceoff,
                      const float* __restrict__ bias, int do_relu,
                      float* __restrict__ out) {
    int tid = blockIdx.x * blockDim.x + threadIdx.x;
    int n = tid >> 5;
    if (n >= N_NODES) return;
    int c = tid & 31, hh = c >> 4;
    int st = rowptr[n], en = rowptr[n + 1];
    float ce = params[ceoff + hh];
    float adn = adst[n * 2 + hh];
    float acc = 0.f, ssum = 0.f;
    int e = st;
    for (; e + 3 < en; e += 4) {
        int2 r0 = epack[e], r1 = epack[e + 1], r2 = epack[e + 2], r3 = epack[e + 3];
        int s0 = r0.x >> BSH, s1 = r1.x >> BSH, s2 = r2.x >> BSH, s3 = r3.x >> BSH;
        float a0 = asrc[s0 * 2 + hh], a1 = asrc[s1 * 2 + hh];
        float a2 = asrc[s2 * 2 + hh], a3 = asrc[s3 * 2 + hh];
        float h0 = h[(size_t)s0 * HC + c], h1 = h[(size_t)s1 * HC + c];
        float h2 = h[(size_t)s2 * HC + c], h3 = h[(size_t)s3 * HC + c];
        float w0 = __expf(lrelu(a0 + adn + ce * __int_as_float(r0.y)));
        float w1 = __expf(lrelu(a1 + adn + ce * __int_as_float(r1.y)));
        float w2 = __expf(lrelu(a2 + adn + ce * __int_as_float(r2.y)));
        float w3 = __expf(lrelu(a3 + adn + ce * __int_as_float(r3.y)));
        acc = fmaf(w0, h0, acc); ssum += w0;
        acc = fmaf(w1, h1, acc); ssum += w1;
        acc = fmaf(w2, h2, acc); ssum += w2;
        acc = fmaf(w3, h3, acc); ssum += w3;
    }
    for (; e < en; ++e) {
        int2 r = epack[e];
        int sv = r.x >> BSH;
        float asv = asrc[sv * 2 + hh];
        float hv = h[(size_t)sv * HC + c];
        float wv = __expf(lrelu(asv + adn + ce * __int_as_float(r.y)));
        acc = fmaf(wv, hv, acc);
        ssum += wv;
    }
    // self-loop (eattr = mean)
    float wself = __expf(lrelu(asrc[n * 2 + hh] + adn + ce * params[1]));
    acc = fmaf(wself, h[(size_t)n * HC + c], acc);
    ssum += wself;
    float v = acc / (ssum + 1e-16f) + bias[c];
    if (do_relu) v = fmaxf(v, 0.f);
    out[(size_t)n * HC + c] = v;
}

// ---------- batch pooling (batch is sorted) ----------

__global__ void k_bounds(const int* __restrict__ batch, int* __restrict__ se) {
    int i = blockIdx.x * blockDim.x + threadIdx.x;
    if (i >= N_NODES) return;
    int b = batch[i];
    if (i == 0 || batch[i - 1] != b) se[b] = i;
    if (i == N_NODES - 1 || batch[i + 1] != b) se[NGRAPH + b] = i + 1;
}

__global__ void k_pool(const float* __restrict__ feat, const int* __restrict__ se,
                       float* __restrict__ emb) {
    int g = blockIdx.x;
    int st = se[g], en = se[NGRAPH + g];
    int c = threadIdx.x & 31, r = threadIdx.x >> 5;  // r in 0..7
    float acc = 0.f;
    for (int n = st + r; n < en; n += 8) acc += feat[(size_t)n * HC + c];
    __shared__ float sh[8][32];
    sh[r][c] = acc;
    __syncthreads();
    if (threadIdx.x < 32) {
        float t = 0.f;
        for (int r2 = 0; r2 < 8; ++r2) t += sh[r2][c];
        int cnt = en - st;
        emb[g * HC + c] = t / (float)(cnt > 0 ? cnt : 1);
    }
}

// ---------- tiny MLP head ----------

__global__ void k_mlp(const float* __restrict__ emb, const float* __restrict__ Wf1,
                      const float* __restrict__ bf1, const float* __restrict__ Wf2,
                      const float* __restrict__ bf2, float* __restrict__ out) {
    int g = blockIdx.x, j = threadIdx.x;  // 32 threads
    __shared__ float hid[32];
    float a = bf1[j];
    for (int k = 0; k < 32; ++k) a = fmaf(emb[g * 32 + k], Wf1[k * 32 + j], a);
    hid[j] = fmaxf(a, 0.f);
    __syncthreads();
    if (j < 2) {
        float o = bf2[j];
        for (int k = 0; k < 32; ++k) o = fmaf(hid[k], Wf2[k * 2 + j], o);
        out[g * 2 + j] = o;
    }
}

extern "C" void kernel_launch(void* const* d_in, const int* in_sizes, int n_in,
                              void* d_out, int out_size, void* d_ws, size_t ws_size,
                              hipStream_t stream) {
    const float* x   = (const float*)d_in[0];
    const int*   ei  = (const int*)d_in[1];
    const float* ea  = (const float*)d_in[2];
    const int* batch = (const int*)d_in[3];
    const float* W1  = (const float*)d_in[4];
    const float* as1 = (const float*)d_in[5];
    const float* ad1 = (const float*)d_in[6];
    const float* We1 = (const float*)d_in[7];
    const float* ae1 = (const float*)d_in[8];
    const float* b1  = (const float*)d_in[9];
    const float* W2  = (const float*)d_in[10];
    const float* as2 = (const float*)d_in[11];
    const float* ad2 = (const float*)d_in[12];
    const float* We2 = (const float*)d_in[13];
    const float* ae2 = (const float*)d_in[14];
    const float* b2  = (const float*)d_in[15];
    const float* Wf1 = (const float*)d_in[16];
    const float* bf1 = (const float*)d_in[17];
    const float* Wf2 = (const float*)d_in[18];
    const float* bf2 = (const float*)d_in[19];
    float* out = (float*)d_out;
    (void)in_sizes; (void)n_in; (void)out_size; (void)ws_size;

    const int* srcp = ei;
    const int* dstp = ei + N_EDGES;

    char* wsb = (char*)d_ws;
    size_t off = 0;
    auto alloc = [&](size_t bytes) -> char* {
        char* p = wsb + off;
        off = (off + bytes + 255) & ~(size_t)255;
        return p;
    };
    float* params = (float*)alloc(64);
    // region A: staged (25.6 MB), reused after k_scatter as hbuf (12.8) + obuf (12.8)
    char* regA = alloc((size_t)N_EDGES * 8 + 4096);
    int2*  staged = (int2*)regA;
    float* hbuf   = (float*)regA;
    float* obuf   = (float*)(regA + (size_t)N_NODES * HC * 4);
    int2*  epack  = (int2*)alloc((size_t)N_EDGES * 8);
    float* asrc   = (float*)alloc((size_t)N_NODES * 2 * 4);
    float* adst   = (float*)alloc((size_t)N_NODES * 2 * 4);
    int*   cnt    = (int*)alloc((size_t)NB2 * 4);
    int*   gstart = (int*)alloc((size_t)(NB2 + 1) * 4);
    int*   gcur   = (int*)alloc((size_t)NB2 * 4);
    int*   rowptr = (int*)alloc((size_t)(N_NODES + 1) * 4);
    float* emb    = (float*)alloc(NGRAPH * HC * 4);
    int*   se     = (int*)alloc(2 * NGRAPH * 4);

    hipMemsetAsync(params, 0, 64, stream);
    hipMemsetAsync(cnt, 0, (size_t)NB2 * 4, stream);
    hipMemsetAsync(se, 0, 2 * NGRAPH * 4, stream);

    const int nThr = N_NODES * HC;  // 3.2M
    const int nBlk = (nThr + 255) / 256;
    const int nBlkN = (N_NODES + 255) / 256;
    const int nBlkB = (N_EDGES + EPB2 - 1) / EPB2;

    // precompute + two-pass locality-aware counting sort (builds rowptr + epack)
    k_ea_sum<<<1024, 256, 0, stream>>>(ea, params);
    k_prep<<<1, 64, 0, stream>>>(We1, ae1, We2, ae2, params);
    k_bhist<<<1024, 256, 0, stream>>>(dstp, cnt);
    k_bscan<<<1, 256, 0, stream>>>(cnt, gstart, gcur, rowptr);
    k_bucket<<<nBlkB, 256, 0, stream>>>(srcp, dstp, ea, gcur, staged);
    k_scatter<<<NB2, 256, 0, stream>>>(staged, gstart, rowptr, epack);

    // ----- layer 1 (hbuf/obuf overwrite staged region; stream-ordered, safe) -----
    k_linear<F_IN><<<nBlk, 256, 0, stream>>>(x, W1, as1, ad1, hbuf, asrc, adst);
    k_gat<<<nBlk, 256, 0, stream>>>(rowptr, epack, hbuf, asrc, adst, params, 2, b1, 1, obuf);

    // ----- layer 2 -----
    k_linear<HC><<<nBlk, 256, 0, stream>>>(obuf, W2, as2, ad2, hbuf, asrc, adst);
    k_gat<<<nBlk, 256, 0, stream>>>(rowptr, epack, hbuf, asrc, adst, params, 4, b2, 0, obuf);

    // ----- pool + MLP -----
    k_bounds<<<nBlkN, 256, 0, stream>>>(batch, se);
    k_pool<<<NGRAPH, 256, 0, stream>>>(obuf, se, emb);
    k_mlp<<<NGRAPH, 32, 0, stream>>>(emb, Wf1, bf1, Wf2, bf2, out);
}

// Round 6
// 545.056 us; speedup vs baseline: 3.5449x; 1.1560x over previous
//
#include <hip/hip_runtime.h>

#define N_NODES 100000
#define N_EDGES 3200000
#define F_IN    128
#define HC      32      // H*C
#define CH      16      // C per head
#define NGRAPH  64
#define NEG     0.2f

#define BSH   7                                   // 128 nodes per bucket
#define BNODE (1 << BSH)
#define NB2   ((N_NODES + BNODE - 1) >> BSH)      // 782 buckets
#define EPB2  8192                                // edges per k_bucket block

__device__ __forceinline__ float lrelu(float x) { return x > 0.f ? x : NEG * x; }

// ---------- reductions / small precompute ----------

__global__ void k_ea_sum(const float* __restrict__ ea, float* __restrict__ params) {
    float acc = 0.f;
    for (int i = blockIdx.x * blockDim.x + threadIdx.x; i < N_EDGES;
         i += gridDim.x * blockDim.x)
        acc += ea[i];
    for (int m = 32; m >= 1; m >>= 1) acc += __shfl_xor(acc, m, 64);
    __shared__ float sh[4];
    int lane = threadIdx.x & 63, wid = threadIdx.x >> 6;
    if (lane == 0) sh[wid] = acc;
    __syncthreads();
    if (threadIdx.x == 0) {
        float t = 0.f;
        for (int i = 0; i < 4; ++i) t += sh[i];
        unsafeAtomicAdd(params, t);
    }
}

// params: [0]=ea_sum, [1]=ea_mean, [2..3]=ce layer1, [4..5]=ce layer2
__global__ void k_prep(const float* __restrict__ We1, const float* __restrict__ ae1,
                       const float* __restrict__ We2, const float* __restrict__ ae2,
                       float* __restrict__ params) {
    int t = threadIdx.x;
    if (t < 2) {
        float c1 = 0.f, c2 = 0.f;
        for (int c = 0; c < CH; ++c) {
            c1 += We1[t * CH + c] * ae1[t * CH + c];
            c2 += We2[t * CH + c] * ae2[t * CH + c];
        }
        params[2 + t] = c1;
        params[4 + t] = c2;
        if (t == 0) params[1] = params[0] / (float)N_EDGES;
    }
}

// ---------- bucket histogram (782 bins) + scan ----------

__global__ void k_bhist(const int* __restrict__ dst, int* __restrict__ cnt) {
    __shared__ int l[NB2];
    for (int i = threadIdx.x; i < NB2; i += 256) l[i] = 0;
    __syncthreads();
    for (int e = blockIdx.x * blockDim.x + threadIdx.x; e < N_EDGES;
         e += gridDim.x * blockDim.x)
        atomicAdd(&l[dst[e] >> BSH], 1);
    __syncthreads();
    for (int i = threadIdx.x; i < NB2; i += 256)
        if (l[i]) atomicAdd(&cnt[i], l[i]);
}

__global__ void k_bscan(const int* __restrict__ cnt, int* __restrict__ gstart,
                        int* __restrict__ gcur, int* __restrict__ rowptr) {
    __shared__ int sh[256];
    int t = threadIdx.x;
    int v[4];
    int s = 0;
    for (int j = 0; j < 4; ++j) {
        int i = t * 4 + j;
        v[j] = (i < NB2) ? cnt[i] : 0;
        s += v[j];
    }
    sh[t] = s;
    __syncthreads();
    for (int off = 1; off < 256; off <<= 1) {
        int u = (t >= off) ? sh[t - off] : 0;
        __syncthreads();
        sh[t] += u;
        __syncthreads();
    }
    int ex = sh[t] - s;   // exclusive prefix
    for (int j = 0; j < 4; ++j) {
        int i = t * 4 + j;
        if (i < NB2) { gstart[i] = ex; gcur[i] = ex; ex += v[j]; }
    }
    if (t == 255) {
        gstart[NB2] = N_EDGES;
        rowptr[N_NODES] = N_EDGES;
    }
}

// ---------- pass A: bucket scatter (packed 8B records) ----------

__global__ void k_bucket(const int* __restrict__ src, const int* __restrict__ dst,
                         const float* __restrict__ ea, int* __restrict__ gcur,
                         int2* __restrict__ staged) {
    __shared__ int lcur[NB2];
    __shared__ int gbase[NB2];
    int t = threadIdx.x;
    for (int i = t; i < NB2; i += 256) lcur[i] = 0;
    __syncthreads();
    int base = blockIdx.x * EPB2;
    int rank[EPB2 / 256];
#pragma unroll
    for (int i = 0; i < EPB2 / 256; ++i) {
        int e = base + i * 256 + t;
        if (e < N_EDGES) rank[i] = atomicAdd(&lcur[dst[e] >> BSH], 1);
    }
    __syncthreads();
    for (int i = t; i < NB2; i += 256)
        if (lcur[i] > 0) gbase[i] = atomicAdd(&gcur[i], lcur[i]);
    __syncthreads();
#pragma unroll
    for (int i = 0; i < EPB2 / 256; ++i) {
        int e = base + i * 256 + t;
        if (e < N_EDGES) {
            int dv = dst[e];
            staged[gbase[dv >> BSH] + rank[i]] =
                make_int2((src[e] << BSH) | (dv & (BNODE - 1)), __float_as_int(ea[e]));
        }
    }
}

// ---------- pass B: per-bucket local hist+scan, write rowptr + per-node-sorted epack ----------

__global__ void k_scatter(const int2* __restrict__ staged, const int* __restrict__ gstart,
                          int* __restrict__ rowptr, int2* __restrict__ epack) {
    __shared__ int cntl[BNODE];
    __shared__ int scanb[BNODE];
    __shared__ int cur[BNODE];
    int b = blockIdx.x, t = threadIdx.x;
    int nbase = b << BSH;
    int bcount = N_NODES - nbase;
    if (bcount > BNODE) bcount = BNODE;
    if (t < BNODE) cntl[t] = 0;
    __syncthreads();
    int st = gstart[b], en = gstart[b + 1];
    for (int e = st + t; e < en; e += 256)
        atomicAdd(&cntl[staged[e].x & (BNODE - 1)], 1);
    __syncthreads();
    if (t < BNODE) scanb[t] = cntl[t];
    __syncthreads();
    for (int off = 1; off < BNODE; off <<= 1) {
        int u = (t < BNODE && t >= off) ? scanb[t - off] : 0;
        __syncthreads();
        if (t < BNODE) scanb[t] += u;
        __syncthreads();
    }
    if (t < BNODE) {
        int ex = st + scanb[t] - cntl[t];   // exclusive, global
        cur[t] = ex;
        if (t < bcount) rowptr[nbase + t] = ex;
    }
    __syncthreads();
    for (int e = st + t; e < en; e += 256) {
        int2 r = staged[e];
        int pos = atomicAdd(&cur[r.x & (BNODE - 1)], 1);
        epack[pos] = r;
    }
}

// ---------- dense: h = x @ W (LDS-tiled), plus fused asrc/adst ----------
// 64 nodes per block; thread t computes nodes np*2,np*2+1 (np=t>>3) x cols cg*4..+3 (cg=t&7)

#define COLS(ac, xv)                                                     \
    ac[0] = fmaf(xv.x, w0.x, ac[0]); ac[1] = fmaf(xv.x, w0.y, ac[1]);    \
    ac[2] = fmaf(xv.x, w0.z, ac[2]); ac[3] = fmaf(xv.x, w0.w, ac[3]);    \
    ac[0] = fmaf(xv.y, w1.x, ac[0]); ac[1] = fmaf(xv.y, w1.y, ac[1]);    \
    ac[2] = fmaf(xv.y, w1.z, ac[2]); ac[3] = fmaf(xv.y, w1.w, ac[3]);    \
    ac[0] = fmaf(xv.z, w2.x, ac[0]); ac[1] = fmaf(xv.z, w2.y, ac[1]);    \
    ac[2] = fmaf(xv.z, w2.z, ac[2]); ac[3] = fmaf(xv.z, w2.w, ac[3]);    \
    ac[0] = fmaf(xv.w, w3.x, ac[0]); ac[1] = fmaf(xv.w, w3.y, ac[1]);    \
    ac[2] = fmaf(xv.w, w3.z, ac[2]); ac[3] = fmaf(xv.w, w3.w, ac[3]);

template <int FIN>
__global__ __launch_bounds__(256)
void k_linear(const float* __restrict__ x, const float* __restrict__ W,
              const float* __restrict__ a_src, const float* __restrict__ a_dst,
              float* __restrict__ h, float* __restrict__ asrc,
              float* __restrict__ adst) {
    constexpr int PAD = FIN + 4;
    __shared__ float ws[FIN * HC];
    __shared__ float xs[64 * PAD];
    int t = threadIdx.x;
    int nbase = blockIdx.x * 64;
    int bcount = N_NODES - nbase;
    if (bcount > 64) bcount = 64;

    for (int i = t; i < FIN * HC / 4; i += 256)
        ((float4*)ws)[i] = ((const float4*)W)[i];
    const float4* xg = (const float4*)(x + (size_t)nbase * FIN);
    int nf4 = bcount * FIN / 4;
    for (int i = t; i < 64 * FIN / 4; i += 256) {
        if (i < nf4) {
            float4 v = xg[i];
            int flat = i * 4;
            int row = flat / FIN, col = flat % FIN;
            *(float4*)&xs[row * PAD + col] = v;
        }
    }
    __syncthreads();

    int cg = t & 7, np = t >> 3;
    int n0 = np * 2, n1 = n0 + 1;
    float acc0[4] = {0.f, 0.f, 0.f, 0.f};
    float acc1[4] = {0.f, 0.f, 0.f, 0.f};
#pragma unroll
    for (int k = 0; k < FIN; k += 4) {
        float4 xa = *(const float4*)&xs[n0 * PAD + k];
        float4 xb = *(const float4*)&xs[n1 * PAD + k];
        const float4* wp = (const float4*)&ws[k * HC] + cg;
        float4 w0 = wp[0], w1 = wp[8], w2 = wp[16], w3 = wp[24];
        COLS(acc0, xa)
        COLS(acc1, xb)
    }

    // epilogue: store h + fused asrc/adst partial reduction over 4 cg-lanes
    int hh = cg >> 2;
    float s0 = 0.f, d0 = 0.f, s1 = 0.f, d1 = 0.f;
#pragma unroll
    for (int j = 0; j < 4; ++j) {
        float av = a_src[hh * CH + (cg & 3) * 4 + j];
        float dv = a_dst[hh * CH + (cg & 3) * 4 + j];
        s0 = fmaf(acc0[j], av, s0); d0 = fmaf(acc0[j], dv, d0);
        s1 = fmaf(acc1[j], av, s1); d1 = fmaf(acc1[j], dv, d1);
    }
    s0 += __shfl_xor(s0, 1, 64); s0 += __shfl_xor(s0, 2, 64);
    d0 += __shfl_xor(d0, 1, 64); d0 += __shfl_xor(d0, 2, 64);
    s1 += __shfl_xor(s1, 1, 64); s1 += __shfl_xor(s1, 2, 64);
    d1 += __shfl_xor(d1, 1, 64); d1 += __shfl_xor(d1, 2, 64);

    if (n0 < bcount) {
        *(float4*)&h[(size_t)(nbase + n0) * HC + cg * 4] =
            make_float4(acc0[0], acc0[1], acc0[2], acc0[3]);
        if ((cg & 3) == 0) {
            asrc[(nbase + n0) * 2 + hh] = s0;
            adst[(nbase + n0) * 2 + hh] = d0;
        }
    }
    if (n1 < bcount) {
        *(float4*)&h[(size_t)(nbase + n1) * HC + cg * 4] =
            make_float4(acc1[0], acc1[1], acc1[2], acc1[3]);
        if ((cg & 3) == 0) {
            asrc[(nbase + n1) * 2 + hh] = s1;
            adst[(nbase + n1) * 2 + hh] = d1;
        }
    }
}

// ---------- fused GAT layer: gather form, register accumulate, 4x unrolled ----------

__global__ void k_gat(const int* __restrict__ rowptr, const int2* __restrict__ epack,
                      const float* __restrict__ h,
                      const float* __restrict__ asrc, const float* __restrict__ adst,
                      const float* __restrict__ params, int ceoff,
                      const float* __restrict__ bias, int do_relu,
                      float* __restrict__ out) {
    int tid = blockIdx.x * blockDim.x + threadIdx.x;
    int n = tid >> 5;
    if (n >= N_NODES) return;
    int c = tid & 31, hh = c >> 4;
    int st = rowptr[n], en = rowptr[n + 1];
    float ce = params[ceoff + hh];
    float adn = adst[n * 2 + hh];
    float acc = 0.f, ssum = 0.f;
    int e = st;
    for (; e + 3 < en; e += 4) {
        int2 r0 = epack[e], r1 = epack[e + 1], r2 = epack[e + 2], r3 = epack[e + 3];
        int s0 = r0.x >> BSH, s1 = r1.x >> BSH, s2 = r2.x >> BSH, s3 = r3.x >> BSH;
        float a0 = asrc[s0 * 2 + hh], a1 = asrc[s1 * 2 + hh];
        float a2 = asrc[s2 * 2 + hh], a3 = asrc[s3 * 2 + hh];
        float h0 = h[(size_t)s0 * HC + c], h1 = h[(size_t)s1 * HC + c];
        float h2 = h[(size_t)s2 * HC + c], h3 = h[(size_t)s3 * HC + c];
        float w0 = __expf(lrelu(a0 + adn + ce * __int_as_float(r0.y)));
        float w1 = __expf(lrelu(a1 + adn + ce * __int_as_float(r1.y)));
        float w2 = __expf(lrelu(a2 + adn + ce * __int_as_float(r2.y)));
        float w3 = __expf(lrelu(a3 + adn + ce * __int_as_float(r3.y)));
        acc = fmaf(w0, h0, acc); ssum += w0;
        acc = fmaf(w1, h1, acc); ssum += w1;
        acc = fmaf(w2, h2, acc); ssum += w2;
        acc = fmaf(w3, h3, acc); ssum += w3;
    }
    for (; e < en; ++e) {
        int2 r = epack[e];
        int sv = r.x >> BSH;
        float asv = asrc[sv * 2 + hh];
        float hv = h[(size_t)sv * HC + c];
        float wv = __expf(lrelu(asv + adn + ce * __int_as_float(r.y)));
        acc = fmaf(wv, hv, acc);
        ssum += wv;
    }
    // self-loop (eattr = mean)
    float wself = __expf(lrelu(asrc[n * 2 + hh] + adn + ce * params[1]));
    acc = fmaf(wself, h[(size_t)n * HC + c], acc);
    ssum += wself;
    float v = acc / (ssum + 1e-16f) + bias[c];
    if (do_relu) v = fmaxf(v, 0.f);
    out[(size_t)n * HC + c] = v;
}

// ---------- batch pooling (batch is sorted) ----------

__global__ void k_bounds(const int* __restrict__ batch, int* __restrict__ se) {
    int i = blockIdx.x * blockDim.x + threadIdx.x;
    if (i >= N_NODES) return;
    int b = batch[i];
    if (i == 0 || batch[i - 1] != b) se[b] = i;
    if (i == N_NODES - 1 || batch[i + 1] != b) se[NGRAPH + b] = i + 1;
}

__global__ void k_pool(const float* __restrict__ feat, const int* __restrict__ se,
                       float* __restrict__ emb) {
    int g = blockIdx.x;
    int st = se[g], en = se[NGRAPH + g];
    int c = threadIdx.x & 31, r = threadIdx.x >> 5;  // r in 0..7
    float acc = 0.f;
    for (int n = st + r; n < en; n += 8) acc += feat[(size_t)n * HC + c];
    __shared__ float sh[8][32];
    sh[r][c] = acc;
    __syncthreads();
    if (threadIdx.x < 32) {
        float t = 0.f;
        for (int r2 = 0; r2 < 8; ++r2) t += sh[r2][c];
        int cnt = en - st;
        emb[g * HC + c] = t / (float)(cnt > 0 ? cnt : 1);
    }
}

// ---------- tiny MLP head ----------

__global__ void k_mlp(const float* __restrict__ emb, const float* __restrict__ Wf1,
                      const float* __restrict__ bf1, const float* __restrict__ Wf2,
                      const float* __restrict__ bf2, float* __restrict__ out) {
    int g = blockIdx.x, j = threadIdx.x;  // 32 threads
    __shared__ float hid[32];
    float a = bf1[j];
    for (int k = 0; k < 32; ++k) a = fmaf(emb[g * 32 + k], Wf1[k * 32 + j], a);
    hid[j] = fmaxf(a, 0.f);
    __syncthreads();
    if (j < 2) {
        float o = bf2[j];
        for (int k = 0; k < 32; ++k) o = fmaf(hid[k], Wf2[k * 2 + j], o);
        out[g * 2 + j] = o;
    }
}

extern "C" void kernel_launch(void* const* d_in, const int* in_sizes, int n_in,
                              void* d_out, int out_size, void* d_ws, size_t ws_size,
                              hipStream_t stream) {
    const float* x   = (const float*)d_in[0];
    const int*   ei  = (const int*)d_in[1];
    const float* ea  = (const float*)d_in[2];
    const int* batch = (const int*)d_in[3];
    const float* W1  = (const float*)d_in[4];
    const float* as1 = (const float*)d_in[5];
    const float* ad1 = (const float*)d_in[6];
    const float* We1 = (const float*)d_in[7];
    const float* ae1 = (const float*)d_in[8];
    const float* b1  = (const float*)d_in[9];
    const float* W2  = (const float*)d_in[10];
    const float* as2 = (const float*)d_in[11];
    const float* ad2 = (const float*)d_in[12];
    const float* We2 = (const float*)d_in[13];
    const float* ae2 = (const float*)d_in[14];
    const float* b2  = (const float*)d_in[15];
    const float* Wf1 = (const float*)d_in[16];
    const float* bf1 = (const float*)d_in[17];
    const float* Wf2 = (const float*)d_in[18];
    const float* bf2 = (const float*)d_in[19];
    float* out = (float*)d_out;
    (void)in_sizes; (void)n_in; (void)out_size; (void)ws_size;

    const int* srcp = ei;
    const int* dstp = ei + N_EDGES;

    char* wsb = (char*)d_ws;
    size_t off = 0;
    auto alloc = [&](size_t bytes) -> char* {
        char* p = wsb + off;
        off = (off + bytes + 255) & ~(size_t)255;
        return p;
    };
    float* params = (float*)alloc(64);
    // region A: staged (25.6 MB), reused after k_scatter as hbuf (12.8) + obuf (12.8)
    char* regA = alloc((size_t)N_EDGES * 8 + 4096);
    int2*  staged = (int2*)regA;
    float* hbuf   = (float*)regA;
    float* obuf   = (float*)(regA + (size_t)N_NODES * HC * 4);
    int2*  epack  = (int2*)alloc((size_t)N_EDGES * 8);
    float* asrc   = (float*)alloc((size_t)N_NODES * 2 * 4);
    float* adst   = (float*)alloc((size_t)N_NODES * 2 * 4);
    int*   cnt    = (int*)alloc((size_t)NB2 * 4);
    int*   gstart = (int*)alloc((size_t)(NB2 + 1) * 4);
    int*   gcur   = (int*)alloc((size_t)NB2 * 4);
    int*   rowptr = (int*)alloc((size_t)(N_NODES + 1) * 4);
    float* emb    = (float*)alloc(NGRAPH * HC * 4);
    int*   se     = (int*)alloc(2 * NGRAPH * 4);

    hipMemsetAsync(params, 0, 64, stream);
    hipMemsetAsync(cnt, 0, (size_t)NB2 * 4, stream);
    hipMemsetAsync(se, 0, 2 * NGRAPH * 4, stream);

    const int nThr = N_NODES * HC;  // 3.2M
    const int nBlk = (nThr + 255) / 256;
    const int nBlkN = (N_NODES + 255) / 256;
    const int nBlkB = (N_EDGES + EPB2 - 1) / EPB2;
    const int nBlkL = (N_NODES + 63) / 64;

    // precompute + two-pass locality-aware counting sort (builds rowptr + epack)
    k_ea_sum<<<1024, 256, 0, stream>>>(ea, params);
    k_prep<<<1, 64, 0, stream>>>(We1, ae1, We2, ae2, params);
    k_bhist<<<1024, 256, 0, stream>>>(dstp, cnt);
    k_bscan<<<1, 256, 0, stream>>>(cnt, gstart, gcur, rowptr);
    k_bucket<<<nBlkB, 256, 0, stream>>>(srcp, dstp, ea, gcur, staged);
    k_scatter<<<NB2, 256, 0, stream>>>(staged, gstart, rowptr, epack);

    // ----- layer 1 (hbuf/obuf overwrite staged region; stream-ordered, safe) -----
    k_linear<F_IN><<<nBlkL, 256, 0, stream>>>(x, W1, as1, ad1, hbuf, asrc, adst);
    k_gat<<<nBlk, 256, 0, stream>>>(rowptr, epack, hbuf, asrc, adst, params, 2, b1, 1, obuf);

    // ----- layer 2 -----
    k_linear<HC><<<nBlkL, 256, 0, stream>>>(obuf, W2, as2, ad2, hbuf, asrc, adst);
    k_gat<<<nBlk, 256, 0, stream>>>(rowptr, epack, hbuf, asrc, adst, params, 4, b2, 0, obuf);

    // ----- pool + MLP -----
    k_bounds<<<nBlkN, 256, 0, stream>>>(batch, se);
    k_pool<<<NGRAPH, 256, 0, stream>>>(obuf, se, emb);
    k_mlp<<<NGRAPH, 32, 0, stream>>>(emb, Wf1, bf1, Wf2, bf2, out);
}